// Round 7
// baseline (386.886 us; speedup 1.0000x reference)
//
#include <hip/hip_runtime.h>
#include <math.h>

#define NA 50000
#define NE 800000
#define FDIM 128
#define KDIM 64
#define NRI 3
#define NRA 2

// Edge chunk: 262144 edges -> gbuf = 67 MB, L3-resident between gemm and segsum.
#define ECHUNK 262144

typedef unsigned short ushort_t;
typedef unsigned int uint_t;
typedef __attribute__((ext_vector_type(8))) short short8v;
typedef __attribute__((ext_vector_type(4))) float f32x4;
typedef __attribute__((ext_vector_type(4))) unsigned short u16x4;

// ssp(x) = softplus(x) - ln2 via hardware v_exp_f32/v_log_f32.
__device__ __forceinline__ float ssp_f(float x) {
    float e = __expf(-fabsf(x));
    return fmaxf(x, 0.0f) + __logf(1.0f + e) - 0.69314718055994530942f;
}
__device__ __forceinline__ ushort_t f2bf(float x) {
    unsigned u = __float_as_uint(x);
    u += 0x7FFFu + ((u >> 16) & 1u);          // RNE
    return (ushort_t)(u >> 16);
}
__device__ __forceinline__ float bf2f(ushort_t h) {
    return __uint_as_float(((unsigned)h) << 16);
}
__device__ __forceinline__ f32x4 ssp4(f32x4 v) {
    f32x4 r;
    #pragma unroll
    for (int j = 0; j < 4; ++j) r[j] = ssp_f(v[j]);
    return r;
}
__device__ __forceinline__ u16x4 pack4(f32x4 v) {
    u16x4 p;
    #pragma unroll
    for (int j = 0; j < 4; ++j) p[j] = f2bf(v[j]);
    return p;
}

// ---------------------------------------------------------------------------
// Weight pre-convert (once): fp32 -> bf16 into ws.
// wbf layout (ushort offsets): Wdesc@0 (8192), Wi@8192, Wj@24576,
// chain@40960: [Wri1_0,Wri2_0,Wri1_1,Wri2_1,Wri1_2,Wri2_2,Wd,Wra1_0,Wra2_0,Wra1_1,Wra2_1]
// ---------------------------------------------------------------------------
__global__ __launch_bounds__(256) void k_wconv(
    const float* __restrict__ Wdesc, const float* __restrict__ Wi,
    const float* __restrict__ Wj,    const float* __restrict__ Wri1,
    const float* __restrict__ Wri2,  const float* __restrict__ Wd,
    const float* __restrict__ Wra1,  const float* __restrict__ Wra2,
    ushort_t* __restrict__ wbf)
{
    const int seg = blockIdx.y;
    const int idx = blockIdx.x * 2048 + threadIdx.x * 8;
    const float* s; ushort_t* d; int cnt;
    const int CH = 40960;
    switch (seg) {
    case 0: cnt = 8192;  if (idx >= cnt) return; s = Wdesc + idx; d = wbf + idx; break;
    case 1: cnt = 16384; if (idx >= cnt) return; s = Wi + idx;    d = wbf + 8192 + idx; break;
    case 2: cnt = 16384; if (idx >= cnt) return; s = Wj + idx;    d = wbf + 24576 + idx; break;
    case 3: { cnt = 3*16384; if (idx >= cnt) return; int k = idx/16384, o = idx - k*16384;
              s = Wri1 + idx; d = wbf + CH + (2*k)*16384 + o; break; }
    case 4: { cnt = 3*16384; if (idx >= cnt) return; int k = idx/16384, o = idx - k*16384;
              s = Wri2 + idx; d = wbf + CH + (2*k+1)*16384 + o; break; }
    case 5: cnt = 16384; if (idx >= cnt) return; s = Wd + idx; d = wbf + CH + 6*16384 + idx; break;
    case 6: { cnt = 2*16384; if (idx >= cnt) return; int k = idx/16384, o = idx - k*16384;
              s = Wra1 + idx; d = wbf + CH + (7+2*k)*16384 + o; break; }
    default:{ cnt = 2*16384; if (idx >= cnt) return; int k = idx/16384, o = idx - k*16384;
              s = Wra2 + idx; d = wbf + CH + (8+2*k)*16384 + o; break; }
    }
    #pragma unroll
    for (int j = 0; j < 8; ++j) d[j] = f2bf(s[j]);
}

// ---------------------------------------------------------------------------
// Per-atom segment starts
// ---------------------------------------------------------------------------
__global__ __launch_bounds__(256) void k_row_starts(
    const int* __restrict__ idx_i, int* __restrict__ row_start)
{
    int i = blockIdx.x * 256 + threadIdx.x;
    if (i > NA) return;
    if (i == NA) { row_start[NA] = NE; return; }
    int lo = 0, hi = NE;
    while (lo < hi) { int mid = (lo + hi) >> 1; if (idx_i[mid] < i) lo = mid + 1; else hi = mid; }
    row_start[i] = lo;
}

// ---------------------------------------------------------------------------
// Transposed-GEMM helpers. Wave w owns atoms {16w + lrow}; each lane holds
// features {16nf + 4kgrp + r} of its atom. C[row=W-row(feature)][col=act-row(atom)].
// ---------------------------------------------------------------------------
__device__ __forceinline__ void stage_w(const ushort_t* __restrict__ src,
                                        ushort_t (*wlds)[136], int t)
{
    const int r = t >> 1, c0 = (t & 1) * 64;
    const short8v* s = (const short8v*)(src + (size_t)r * FDIM + c0);
    #pragma unroll
    for (int q = 0; q < 8; ++q)
        *(short8v*)&wlds[r][c0 + q * 8] = s[q];
}

__device__ __forceinline__ void gemm_tile_T(
    const ushort_t (*actA)[136], const ushort_t (*wlds)[136],
    int w, int lrow, int kgrp, const float* __restrict__ bias, f32x4 acc[8])
{
    short8v bfr[4];
    #pragma unroll
    for (int ks = 0; ks < 4; ++ks)
        bfr[ks] = *(const short8v*)&actA[16 * w + lrow][ks * 32 + kgrp * 8];
    #pragma unroll
    for (int nf = 0; nf < 8; ++nf)
        acc[nf] = *(const f32x4*)(bias + 16 * nf + 4 * kgrp);
    #pragma unroll
    for (int nf = 0; nf < 8; ++nf)
        #pragma unroll
        for (int ks = 0; ks < 4; ++ks) {
            short8v av = *(const short8v*)&wlds[16 * nf + lrow][ks * 32 + kgrp * 8];
            acc[nf] = __builtin_amdgcn_mfma_f32_16x16x32_bf16(av, bfr[ks], acc[nf], 0, 0, 0);
        }
}

// act = ssp(v), packed b64 writes into this wave's own 16 rows
__device__ __forceinline__ void write_act_T(
    ushort_t (*actA)[136], int w, int lrow, int kgrp, const f32x4 v[8])
{
    #pragma unroll
    for (int nf = 0; nf < 8; ++nf)
        *(u16x4*)&actA[16 * w + lrow][16 * nf + 4 * kgrp] = pack4(ssp4(v[nf]));
}

// ---------------------------------------------------------------------------
// Node pre (MFMA, transposed): xi = ssp(ssp(feat)@Wi.T+bi) -> msg (f32)
//                              xja = ssp(ssp(feat)@Wj.T+bj) -> bf16
// ---------------------------------------------------------------------------
__global__ __launch_bounds__(256) void k_node_pre(
    const float* __restrict__ feat, const ushort_t* __restrict__ wbf,
    const float* __restrict__ bi, const float* __restrict__ bj,
    float* __restrict__ xi_out, ushort_t* __restrict__ xja_out)
{
    __shared__ ushort_t actA[64][136];
    __shared__ ushort_t wlds[128][136];
    const int t = threadIdx.x, lane = t & 63, w = t >> 6;
    const int lrow = lane & 15, kgrp = lane >> 4;
    const int atom = blockIdx.x * 64 + 16 * w + lrow;
    const bool ok = atom < NA;

    f32x4 v[8];
    #pragma unroll
    for (int nf = 0; nf < 8; ++nf)
        v[nf] = ok ? *(const f32x4*)(feat + (size_t)atom * FDIM + 16 * nf + 4 * kgrp)
                   : (f32x4){0.f, 0.f, 0.f, 0.f};
    write_act_T(actA, w, lrow, kgrp, v);
    __syncthreads();
    stage_w(wbf + 8192, wlds, t);
    __syncthreads();
    f32x4 acc[8];
    gemm_tile_T(actA, wlds, w, lrow, kgrp, bi, acc);
    if (ok)
        #pragma unroll
        for (int nf = 0; nf < 8; ++nf)
            *(f32x4*)(xi_out + (size_t)atom * FDIM + 16 * nf + 4 * kgrp) = ssp4(acc[nf]);
    __syncthreads();
    stage_w(wbf + 24576, wlds, t);
    __syncthreads();
    gemm_tile_T(actA, wlds, w, lrow, kgrp, bj, acc);
    if (ok)
        #pragma unroll
        for (int nf = 0; nf < 8; ++nf)
            *(u16x4*)(xja_out + (size_t)atom * FDIM + 16 * nf + 4 * kgrp) = pack4(ssp4(acc[nf]));
}

// ---------------------------------------------------------------------------
// Edge GEMM + gather-multiply (fused): p[e][f] = (desc[e]@Wdesc[f]) * xja[idx_j[e]][f]
// Wdesc A-frags resident in 64 VGPRs/wave; 4 tiles of 16 edges per wave,
// fully unrolled + branch-free in the FULL path so loads pipeline.
// ---------------------------------------------------------------------------
__device__ __forceinline__ short8v pack8(const float* p) {
    short8v r;
    #pragma unroll
    for (int j = 0; j < 8; ++j) r[j] = (short)f2bf(p[j]);
    return r;
}

#define TPW 4   // tiles (of 16 edges) per wave; block covers 4 waves * TPW * 16 = 256 edges

template<bool FULL>
__device__ __forceinline__ void gemm_p_body(
    const float* __restrict__ desc, const short8v a[8][2],
    const int* __restrict__ idx_j, const ushort_t* __restrict__ xja,
    ushort_t* __restrict__ p, int nE, int base, int lrow, int kgrp)
{
    int jj[TPW];
    #pragma unroll
    for (int tt = 0; tt < TPW; ++tt) {
        int er = base + tt * 16 + lrow;
        jj[tt] = (FULL || er < nE) ? idx_j[er] : 0;
    }
    #pragma unroll
    for (int tt = 0; tt < TPW; ++tt) {
        const int er = base + tt * 16 + lrow;
        const bool ok = FULL || (er < nE);
        short8v b0, b1;
        if (ok) {
            const float* q = desc + (size_t)er * KDIM + kgrp * 8;
            float t0[8], t1[8];
            *(float4*)(t0)     = *(const float4*)q;
            *(float4*)(t0 + 4) = *(const float4*)(q + 4);
            *(float4*)(t1)     = *(const float4*)(q + 32);
            *(float4*)(t1 + 4) = *(const float4*)(q + 36);
            b0 = pack8(t0); b1 = pack8(t1);
        } else {
            b0 = (short8v){0,0,0,0,0,0,0,0};
            b1 = b0;
        }
        f32x4 acc[8];
        #pragma unroll
        for (int nf = 0; nf < 8; ++nf) acc[nf] = (f32x4){0.f, 0.f, 0.f, 0.f};
        #pragma unroll
        for (int nf = 0; nf < 8; ++nf) {
            acc[nf] = __builtin_amdgcn_mfma_f32_16x16x32_bf16(a[nf][0], b0, acc[nf], 0,0,0);
            acc[nf] = __builtin_amdgcn_mfma_f32_16x16x32_bf16(a[nf][1], b1, acc[nf], 0,0,0);
        }
        if (ok) {
            #pragma unroll
            for (int nf = 0; nf < 8; ++nf) {
                u16x4 xv = *(const u16x4*)(xja + (size_t)jj[tt] * FDIM + 16 * nf + 4 * kgrp);
                f32x4 pr;
                #pragma unroll
                for (int j = 0; j < 4; ++j) pr[j] = acc[nf][j] * bf2f(xv[j]);
                *(u16x4*)(p + (size_t)er * FDIM + 16 * nf + 4 * kgrp) = pack4(pr);
            }
        }
    }
}

__global__ __launch_bounds__(256) void k_gemm_p(
    const float* __restrict__ desc, const ushort_t* __restrict__ wdbf,
    const int* __restrict__ idx_j,       // chunk-shifted
    const ushort_t* __restrict__ xja,
    ushort_t* __restrict__ p, int nE)
{
    const int t = threadIdx.x, lane = t & 63, w = t >> 6;
    const int lrow = lane & 15, kgrp = lane >> 4;

    short8v a[8][2];
    #pragma unroll
    for (int nf = 0; nf < 8; ++nf)
        #pragma unroll
        for (int ks = 0; ks < 2; ++ks)
            a[nf][ks] = *(const short8v*)(wdbf + (size_t)(16 * nf + lrow) * KDIM
                                          + ks * 32 + kgrp * 8);

    const int base = (blockIdx.x * 4 + w) * (TPW * 16);
    if ((blockIdx.x + 1) * (4 * TPW * 16) <= nE)
        gemm_p_body<true >(desc, a, idx_j, xja, p, nE, base, lrow, kgrp);
    else
        gemm_p_body<false>(desc, a, idx_j, xja, p, nE, base, lrow, kgrp);
}

// ---------------------------------------------------------------------------
// Segmented sum (streaming, no gather): msg[i] += sum_{e in seg(i)} p[e]
// Block (1 wave) per atom; lane t holds features 2t, 2t+1. 4-way unrolled.
// p chunk is L3-resident (written by the immediately preceding k_gemm_p).
// ---------------------------------------------------------------------------
__global__ __launch_bounds__(64) void k_segsum(
    const ushort_t* __restrict__ p,
    const int* __restrict__ row_start,
    float* __restrict__ msg,
    int ce0, int ce1)
{
    const int i = blockIdx.x;
    const int t = threadIdx.x;
    int s = row_start[i], e = row_start[i + 1];
    if (s < ce0) s = ce0;
    if (e > ce1) e = ce1;
    if (s >= e) return;
    const uint_t* pp = (const uint_t*)p;
    int k = s - ce0, kend = e - ce0;
    float a0 = 0.f, a1 = 0.f, b0 = 0.f, b1 = 0.f;
    float c0 = 0.f, c1 = 0.f, d0 = 0.f, d1 = 0.f;
    for (; k + 4 <= kend; k += 4) {
        uint_t v0 = pp[(size_t)(k    ) * 64 + t];
        uint_t v1 = pp[(size_t)(k + 1) * 64 + t];
        uint_t v2 = pp[(size_t)(k + 2) * 64 + t];
        uint_t v3 = pp[(size_t)(k + 3) * 64 + t];
        a0 += __uint_as_float(v0 << 16); a1 += __uint_as_float(v0 & 0xFFFF0000u);
        b0 += __uint_as_float(v1 << 16); b1 += __uint_as_float(v1 & 0xFFFF0000u);
        c0 += __uint_as_float(v2 << 16); c1 += __uint_as_float(v2 & 0xFFFF0000u);
        d0 += __uint_as_float(v3 << 16); d1 += __uint_as_float(v3 & 0xFFFF0000u);
    }
    for (; k < kend; ++k) {
        uint_t v = pp[(size_t)k * 64 + t];
        a0 += __uint_as_float(v << 16); a1 += __uint_as_float(v & 0xFFFF0000u);
    }
    a0 = (a0 + b0) + (c0 + d0);
    a1 = (a1 + b1) + (c1 + d1);
    float2* mp = (float2*)&msg[(size_t)i * FDIM + 2 * t];
    float2 mv = *mp;
    mv.x += a0; mv.y += a1;
    *mp = mv;
}

// ---------------------------------------------------------------------------
// Fallback fused edge kernel (tiny-ws only)
// ---------------------------------------------------------------------------
__global__ __launch_bounds__(128) void k_edge(
    const float* __restrict__ desc,
    const int* __restrict__ idx_i,
    const int* __restrict__ idx_j,
    const float* __restrict__ Wdesc,
    const ushort_t* __restrict__ xja,
    float* __restrict__ msg)
{
    const int i = blockIdx.x;
    const int t = threadIdx.x;
    int lo = 0, hi = NE;
    while (lo < hi) { int mid = (lo + hi) >> 1; if (idx_i[mid] < i) lo = mid + 1; else hi = mid; }
    int start = lo;
    hi = NE;
    while (lo < hi) { int mid = (lo + hi) >> 1; if (idx_i[mid] < i + 1) lo = mid + 1; else hi = mid; }
    int end = lo;
    start = __builtin_amdgcn_readfirstlane(start);
    end   = __builtin_amdgcn_readfirstlane(end);
    if (start >= end) return;
    float wreg[KDIM];
    #pragma unroll
    for (int q = 0; q < KDIM / 4; ++q) {
        float4 wv = *(const float4*)(Wdesc + (size_t)t * KDIM + 4 * q);
        wreg[4*q+0] = wv.x; wreg[4*q+1] = wv.y; wreg[4*q+2] = wv.z; wreg[4*q+3] = wv.w;
    }
    float acc = 0.0f;
    for (int e = start; e < end; ++e) {
        int jj = idx_j[e];
        const float* de = desc + (size_t)e * KDIM;
        float dot = 0.0f;
        #pragma unroll
        for (int q = 0; q < KDIM / 4; ++q) {
            float4 dv = *(const float4*)(de + 4 * q);
            dot += dv.x * wreg[4*q] + dv.y * wreg[4*q+1]
                 + dv.z * wreg[4*q+2] + dv.w * wreg[4*q+3];
        }
        acc += dot * bf2f(xja[(size_t)jj * FDIM + t]);
    }
    msg[(size_t)i * FDIM + t] += acc;
}

// ---------------------------------------------------------------------------
// Fused node chain (transposed): 3 residuals + outmix + 2 residuals.
// m carried as f32x4[8] per thread (atom fixed per lane, features packed).
// ---------------------------------------------------------------------------
__global__ __launch_bounds__(256) void k_chain(
    const float* __restrict__ msgp, const float* __restrict__ feat,
    const float* __restrict__ u, const ushort_t* __restrict__ wch,
    const float* __restrict__ bri1, const float* __restrict__ bri2,
    const float* __restrict__ bd,
    const float* __restrict__ bra1, const float* __restrict__ bra2,
    float* __restrict__ xout)
{
    __shared__ ushort_t actA[64][136];
    __shared__ ushort_t wlds[128][136];
    const int t = threadIdx.x, lane = t & 63, w = t >> 6;
    const int lrow = lane & 15, kgrp = lane >> 4;
    const int atom = blockIdx.x * 64 + 16 * w + lrow;
    const bool ok = atom < NA;

    f32x4 m[8], h[8], acc[8];
    #pragma unroll
    for (int nf = 0; nf < 8; ++nf)
        m[nf] = ok ? *(const f32x4*)(msgp + (size_t)atom * FDIM + 16 * nf + 4 * kgrp)
                   : (f32x4){0.f, 0.f, 0.f, 0.f};

    // --- 3 interaction residuals ---
    for (int k = 0; k < NRI; ++k) {
        write_act_T(actA, w, lrow, kgrp, m);
        __syncthreads();
        stage_w(wch + (size_t)(2 * k) * 16384, wlds, t);
        __syncthreads();
        gemm_tile_T(actA, wlds, w, lrow, kgrp, bri1 + k * FDIM, acc);
        #pragma unroll
        for (int nf = 0; nf < 8; ++nf) h[nf] = acc[nf];
        write_act_T(actA, w, lrow, kgrp, h);
        __syncthreads();
        stage_w(wch + (size_t)(2 * k + 1) * 16384, wlds, t);
        __syncthreads();
        gemm_tile_T(actA, wlds, w, lrow, kgrp, bri2 + k * FDIM, acc);
        #pragma unroll
        for (int nf = 0; nf < 8; ++nf) m[nf] += acc[nf];
    }

    // --- outmix: m = u*feat + ssp(m)@Wd.T + bd ---
    write_act_T(actA, w, lrow, kgrp, m);
    __syncthreads();
    stage_w(wch + (size_t)6 * 16384, wlds, t);
    __syncthreads();
    gemm_tile_T(actA, wlds, w, lrow, kgrp, bd, acc);
    #pragma unroll
    for (int nf = 0; nf < 8; ++nf) {
        f32x4 fv = ok ? *(const f32x4*)(feat + (size_t)atom * FDIM + 16 * nf + 4 * kgrp)
                      : (f32x4){0.f, 0.f, 0.f, 0.f};
        f32x4 uv = *(const f32x4*)(u + 16 * nf + 4 * kgrp);
        m[nf] = uv * fv + acc[nf];
    }

    // --- 2 atomic residuals ---
    for (int k = 0; k < NRA; ++k) {
        write_act_T(actA, w, lrow, kgrp, m);
        __syncthreads();
        stage_w(wch + (size_t)(7 + 2 * k) * 16384, wlds, t);
        __syncthreads();
        gemm_tile_T(actA, wlds, w, lrow, kgrp, bra1 + k * FDIM, acc);
        #pragma unroll
        for (int nf = 0; nf < 8; ++nf) h[nf] = acc[nf];
        write_act_T(actA, w, lrow, kgrp, h);
        __syncthreads();
        stage_w(wch + (size_t)(8 + 2 * k) * 16384, wlds, t);
        __syncthreads();
        gemm_tile_T(actA, wlds, w, lrow, kgrp, bra2 + k * FDIM, acc);
        #pragma unroll
        for (int nf = 0; nf < 8; ++nf) m[nf] += acc[nf];
    }

    if (ok)
        #pragma unroll
        for (int nf = 0; nf < 8; ++nf)
            *(f32x4*)(xout + (size_t)atom * FDIM + 4 * kgrp + 16 * nf) = m[nf];
}

// ---------------------------------------------------------------------------
extern "C" void kernel_launch(void* const* d_in, const int* in_sizes, int n_in,
                              void* d_out, int out_size, void* d_ws, size_t ws_size,
                              hipStream_t stream)
{
    const float* feat  = (const float*)d_in[0];
    const float* desc  = (const float*)d_in[1];
    const int*   idx_i = (const int*)d_in[2];
    const int*   idx_j = (const int*)d_in[3];
    const float* Wdesc = (const float*)d_in[4];
    const float* Wi    = (const float*)d_in[5];
    const float* bi    = (const float*)d_in[6];
    const float* Wj    = (const float*)d_in[7];
    const float* bj    = (const float*)d_in[8];
    const float* Wri1  = (const float*)d_in[9];
    const float* bri1  = (const float*)d_in[10];
    const float* Wri2  = (const float*)d_in[11];
    const float* bri2  = (const float*)d_in[12];
    const float* Wd    = (const float*)d_in[13];
    const float* bd    = (const float*)d_in[14];
    const float* u     = (const float*)d_in[15];
    const float* Wra1  = (const float*)d_in[16];
    const float* bra1  = (const float*)d_in[17];
    const float* Wra2  = (const float*)d_in[18];
    const float* bra2  = (const float*)d_in[19];

    char* wsp = (char*)d_ws;
    float* msg = (float*)wsp;
    size_t off = (size_t)NA * FDIM * sizeof(float);
    ushort_t* xja = (ushort_t*)(wsp + off);
    off += (size_t)NA * FDIM * sizeof(ushort_t);
    int* row_start = (int*)(wsp + off);
    off += (((size_t)(NA + 1) * sizeof(int)) + 255) & ~(size_t)255;
    ushort_t* wbf = (ushort_t*)(wsp + off);
    off += (((size_t)221184 * sizeof(ushort_t)) + 255) & ~(size_t)255;
    ushort_t* gbuf = (ushort_t*)(wsp + off);
    size_t avail = (ws_size > off) ? ws_size - off : 0;
    size_t max_chunk = (avail / ((size_t)FDIM * sizeof(ushort_t))) & ~(size_t)255;
    if (max_chunk > ECHUNK) max_chunk = ECHUNK;   // keep gbuf L3-resident

    float* xout = (float*)d_out;
    const int nblk64 = (NA + 63) / 64;

    k_wconv<<<dim3(24, 8), 256, 0, stream>>>(Wdesc, Wi, Wj, Wri1, Wri2, Wd, Wra1, Wra2, wbf);
    k_row_starts<<<(NA + 256) / 256, 256, 0, stream>>>(idx_i, row_start);
    k_node_pre<<<nblk64, 256, 0, stream>>>(feat, wbf, bi, bj, msg, xja);

    if (max_chunk >= 256) {
        for (size_t ce0 = 0; ce0 < NE; ce0 += max_chunk) {
            size_t ce1 = ce0 + max_chunk; if (ce1 > NE) ce1 = NE;
            int n = (int)(ce1 - ce0);
            k_gemm_p<<<(n + 255) / 256, 256, 0, stream>>>(desc + ce0 * KDIM, wbf,
                                                          idx_j + ce0, xja, gbuf, n);
            k_segsum<<<NA, 64, 0, stream>>>(gbuf, row_start, msg, (int)ce0, (int)ce1);
        }
    } else {
        k_edge<<<NA, 128, 0, stream>>>(desc, idx_i, idx_j, Wdesc, xja, msg);
    }

    k_chain<<<nblk64, 256, 0, stream>>>(msg, feat, u, wbf + 40960,
                                        bri1, bri2, bd, bra1, bra2, xout);
}

// Round 8
// 343.610 us; speedup vs baseline: 1.1259x; 1.1259x over previous
//
#include <hip/hip_runtime.h>
#include <math.h>

#define NA 50000
#define NE 800000
#define FDIM 128
#define KDIM 64
#define NRI 3
#define NRA 2

typedef unsigned short ushort_t;
typedef unsigned int uint_t;
typedef __attribute__((ext_vector_type(8))) short short8v;
typedef __attribute__((ext_vector_type(4))) float f32x4;
typedef __attribute__((ext_vector_type(4))) unsigned short u16x4;

// ssp(x) = softplus(x) - ln2 via hardware v_exp_f32/v_log_f32.
__device__ __forceinline__ float ssp_f(float x) {
    float e = __expf(-fabsf(x));
    return fmaxf(x, 0.0f) + __logf(1.0f + e) - 0.69314718055994530942f;
}
__device__ __forceinline__ ushort_t f2bf(float x) {
    unsigned u = __float_as_uint(x);
    u += 0x7FFFu + ((u >> 16) & 1u);          // RNE
    return (ushort_t)(u >> 16);
}
__device__ __forceinline__ float bf2f(ushort_t h) {
    return __uint_as_float(((unsigned)h) << 16);
}
__device__ __forceinline__ f32x4 ssp4(f32x4 v) {
    f32x4 r;
    #pragma unroll
    for (int j = 0; j < 4; ++j) r[j] = ssp_f(v[j]);
    return r;
}
__device__ __forceinline__ u16x4 pack4(f32x4 v) {
    u16x4 p;
    #pragma unroll
    for (int j = 0; j < 4; ++j) p[j] = f2bf(v[j]);
    return p;
}

// ---------------------------------------------------------------------------
// Weight pre-convert (once): fp32 -> bf16 into ws.
// wbf layout (ushort offsets): Wdesc@0 (8192), Wi@8192, Wj@24576,
// chain@40960: [Wri1_0,Wri2_0,Wri1_1,Wri2_1,Wri1_2,Wri2_2,Wd,Wra1_0,Wra2_0,Wra1_1,Wra2_1]
// ---------------------------------------------------------------------------
__global__ __launch_bounds__(256) void k_wconv(
    const float* __restrict__ Wdesc, const float* __restrict__ Wi,
    const float* __restrict__ Wj,    const float* __restrict__ Wri1,
    const float* __restrict__ Wri2,  const float* __restrict__ Wd,
    const float* __restrict__ Wra1,  const float* __restrict__ Wra2,
    ushort_t* __restrict__ wbf)
{
    const int seg = blockIdx.y;
    const int idx = blockIdx.x * 2048 + threadIdx.x * 8;
    const float* s; ushort_t* d; int cnt;
    const int CH = 40960;
    switch (seg) {
    case 0: cnt = 8192;  if (idx >= cnt) return; s = Wdesc + idx; d = wbf + idx; break;
    case 1: cnt = 16384; if (idx >= cnt) return; s = Wi + idx;    d = wbf + 8192 + idx; break;
    case 2: cnt = 16384; if (idx >= cnt) return; s = Wj + idx;    d = wbf + 24576 + idx; break;
    case 3: { cnt = 3*16384; if (idx >= cnt) return; int k = idx/16384, o = idx - k*16384;
              s = Wri1 + idx; d = wbf + CH + (2*k)*16384 + o; break; }
    case 4: { cnt = 3*16384; if (idx >= cnt) return; int k = idx/16384, o = idx - k*16384;
              s = Wri2 + idx; d = wbf + CH + (2*k+1)*16384 + o; break; }
    case 5: cnt = 16384; if (idx >= cnt) return; s = Wd + idx; d = wbf + CH + 6*16384 + idx; break;
    case 6: { cnt = 2*16384; if (idx >= cnt) return; int k = idx/16384, o = idx - k*16384;
              s = Wra1 + idx; d = wbf + CH + (7+2*k)*16384 + o; break; }
    default:{ cnt = 2*16384; if (idx >= cnt) return; int k = idx/16384, o = idx - k*16384;
              s = Wra2 + idx; d = wbf + CH + (8+2*k)*16384 + o; break; }
    }
    #pragma unroll
    for (int j = 0; j < 8; ++j) d[j] = f2bf(s[j]);
}

// ---------------------------------------------------------------------------
// Per-atom segment starts
// ---------------------------------------------------------------------------
__global__ __launch_bounds__(256) void k_row_starts(
    const int* __restrict__ idx_i, int* __restrict__ row_start)
{
    int i = blockIdx.x * 256 + threadIdx.x;
    if (i > NA) return;
    if (i == NA) { row_start[NA] = NE; return; }
    int lo = 0, hi = NE;
    while (lo < hi) { int mid = (lo + hi) >> 1; if (idx_i[mid] < i) lo = mid + 1; else hi = mid; }
    row_start[i] = lo;
}

// ---------------------------------------------------------------------------
// Transposed-GEMM helpers. Wave w owns atoms {16w + lrow}; each lane holds
// features {16nf + 4kgrp + r} of its atom. C[row=W-row(feature)][col=act-row(atom)].
// ---------------------------------------------------------------------------
__device__ __forceinline__ void stage_w(const ushort_t* __restrict__ src,
                                        ushort_t (*wlds)[136], int t)
{
    const int r = t >> 1, c0 = (t & 1) * 64;
    const short8v* s = (const short8v*)(src + (size_t)r * FDIM + c0);
    #pragma unroll
    for (int q = 0; q < 8; ++q)
        *(short8v*)&wlds[r][c0 + q * 8] = s[q];
}

__device__ __forceinline__ void gemm_tile_T(
    const ushort_t (*actA)[136], const ushort_t (*wlds)[136],
    int w, int lrow, int kgrp, const float* __restrict__ bias, f32x4 acc[8])
{
    short8v bfr[4];
    #pragma unroll
    for (int ks = 0; ks < 4; ++ks)
        bfr[ks] = *(const short8v*)&actA[16 * w + lrow][ks * 32 + kgrp * 8];
    #pragma unroll
    for (int nf = 0; nf < 8; ++nf)
        acc[nf] = *(const f32x4*)(bias + 16 * nf + 4 * kgrp);
    #pragma unroll
    for (int nf = 0; nf < 8; ++nf)
        #pragma unroll
        for (int ks = 0; ks < 4; ++ks) {
            short8v av = *(const short8v*)&wlds[16 * nf + lrow][ks * 32 + kgrp * 8];
            acc[nf] = __builtin_amdgcn_mfma_f32_16x16x32_bf16(av, bfr[ks], acc[nf], 0, 0, 0);
        }
}

// act = ssp(v), packed b64 writes into this wave's own 16 rows
__device__ __forceinline__ void write_act_T(
    ushort_t (*actA)[136], int w, int lrow, int kgrp, const f32x4 v[8])
{
    #pragma unroll
    for (int nf = 0; nf < 8; ++nf)
        *(u16x4*)&actA[16 * w + lrow][16 * nf + 4 * kgrp] = pack4(ssp4(v[nf]));
}

// ---------------------------------------------------------------------------
// Node pre (MFMA, transposed): xi = ssp(ssp(feat)@Wi.T+bi) -> msg (f32)
//                              xja = ssp(ssp(feat)@Wj.T+bj) -> bf16
// ---------------------------------------------------------------------------
__global__ __launch_bounds__(256) void k_node_pre(
    const float* __restrict__ feat, const ushort_t* __restrict__ wbf,
    const float* __restrict__ bi, const float* __restrict__ bj,
    float* __restrict__ xi_out, ushort_t* __restrict__ xja_out)
{
    __shared__ ushort_t actA[64][136];
    __shared__ ushort_t wlds[128][136];
    const int t = threadIdx.x, lane = t & 63, w = t >> 6;
    const int lrow = lane & 15, kgrp = lane >> 4;
    const int atom = blockIdx.x * 64 + 16 * w + lrow;
    const bool ok = atom < NA;

    f32x4 v[8];
    #pragma unroll
    for (int nf = 0; nf < 8; ++nf)
        v[nf] = ok ? *(const f32x4*)(feat + (size_t)atom * FDIM + 16 * nf + 4 * kgrp)
                   : (f32x4){0.f, 0.f, 0.f, 0.f};
    write_act_T(actA, w, lrow, kgrp, v);
    __syncthreads();
    stage_w(wbf + 8192, wlds, t);
    __syncthreads();
    f32x4 acc[8];
    gemm_tile_T(actA, wlds, w, lrow, kgrp, bi, acc);
    if (ok)
        #pragma unroll
        for (int nf = 0; nf < 8; ++nf)
            *(f32x4*)(xi_out + (size_t)atom * FDIM + 16 * nf + 4 * kgrp) = ssp4(acc[nf]);
    __syncthreads();
    stage_w(wbf + 24576, wlds, t);
    __syncthreads();
    gemm_tile_T(actA, wlds, w, lrow, kgrp, bj, acc);
    if (ok)
        #pragma unroll
        for (int nf = 0; nf < 8; ++nf)
            *(u16x4*)(xja_out + (size_t)atom * FDIM + 16 * nf + 4 * kgrp) = pack4(ssp4(acc[nf]));
}

// ---------------------------------------------------------------------------
// Edge GEMM + gather-multiply (fused): p[e][f] = (desc[e]@Wdesc[f]) * xja[idx_j[e]][f]
// Wdesc A-frags resident in 64 VGPRs/wave; 8 tiles of 16 edges per wave,
// FULL path is branch-free and fully unrolled -> scheduler pipelines loads
// across tiles (idx_j hoisted to top; desc/gather loads hoisted by unroll).
// ---------------------------------------------------------------------------
__device__ __forceinline__ short8v pack8(const float* p) {
    short8v r;
    #pragma unroll
    for (int j = 0; j < 8; ++j) r[j] = (short)f2bf(p[j]);
    return r;
}

#define TPW 8   // tiles (of 16 edges) per wave; block covers 4 waves * TPW * 16 = 512 edges

template<bool FULL>
__device__ __forceinline__ void gemm_p_body(
    const float* __restrict__ desc, const short8v a[8][2],
    const int* __restrict__ idx_j, const ushort_t* __restrict__ xja,
    ushort_t* __restrict__ p, int nE, int base, int lrow, int kgrp)
{
    int jj[TPW];
    #pragma unroll
    for (int tt = 0; tt < TPW; ++tt) {
        int er = base + tt * 16 + lrow;
        jj[tt] = (FULL || er < nE) ? idx_j[er] : 0;
    }
    #pragma unroll
    for (int tt = 0; tt < TPW; ++tt) {
        const int er = base + tt * 16 + lrow;
        const bool ok = FULL || (er < nE);
        short8v b0, b1;
        if (ok) {
            const float* q = desc + (size_t)er * KDIM + kgrp * 8;
            float t0[8], t1[8];
            *(float4*)(t0)     = *(const float4*)q;
            *(float4*)(t0 + 4) = *(const float4*)(q + 4);
            *(float4*)(t1)     = *(const float4*)(q + 32);
            *(float4*)(t1 + 4) = *(const float4*)(q + 36);
            b0 = pack8(t0); b1 = pack8(t1);
        } else {
            b0 = (short8v){0,0,0,0,0,0,0,0};
            b1 = b0;
        }
        f32x4 acc[8];
        #pragma unroll
        for (int nf = 0; nf < 8; ++nf) acc[nf] = (f32x4){0.f, 0.f, 0.f, 0.f};
        #pragma unroll
        for (int nf = 0; nf < 8; ++nf) {
            acc[nf] = __builtin_amdgcn_mfma_f32_16x16x32_bf16(a[nf][0], b0, acc[nf], 0,0,0);
            acc[nf] = __builtin_amdgcn_mfma_f32_16x16x32_bf16(a[nf][1], b1, acc[nf], 0,0,0);
        }
        if (ok) {
            #pragma unroll
            for (int nf = 0; nf < 8; ++nf) {
                u16x4 xv = *(const u16x4*)(xja + (size_t)jj[tt] * FDIM + 16 * nf + 4 * kgrp);
                f32x4 pr;
                #pragma unroll
                for (int j = 0; j < 4; ++j) pr[j] = acc[nf][j] * bf2f(xv[j]);
                *(u16x4*)(p + (size_t)er * FDIM + 16 * nf + 4 * kgrp) = pack4(pr);
            }
        }
    }
}

__global__ __launch_bounds__(256, 2) void k_gemm_p(
    const float* __restrict__ desc, const ushort_t* __restrict__ wdbf,
    const int* __restrict__ idx_j,
    const ushort_t* __restrict__ xja,
    ushort_t* __restrict__ p, int nE)
{
    const int t = threadIdx.x, lane = t & 63, w = t >> 6;
    const int lrow = lane & 15, kgrp = lane >> 4;

    short8v a[8][2];
    #pragma unroll
    for (int nf = 0; nf < 8; ++nf)
        #pragma unroll
        for (int ks = 0; ks < 2; ++ks)
            a[nf][ks] = *(const short8v*)(wdbf + (size_t)(16 * nf + lrow) * KDIM
                                          + ks * 32 + kgrp * 8);

    const int base = (blockIdx.x * 4 + w) * (TPW * 16);
    if ((blockIdx.x + 1) * (4 * TPW * 16) <= nE)
        gemm_p_body<true >(desc, a, idx_j, xja, p, nE, base, lrow, kgrp);
    else
        gemm_p_body<false>(desc, a, idx_j, xja, p, nE, base, lrow, kgrp);
}

// ---------------------------------------------------------------------------
// Segmented sum (streaming, no gather): msg[i] += sum_{e in seg(i)} p[e]
// Block (1 wave) per atom; lane t holds features 2t, 2t+1. 8-way unrolled.
// ---------------------------------------------------------------------------
__global__ __launch_bounds__(64) void k_segsum(
    const ushort_t* __restrict__ p,
    const int* __restrict__ row_start,
    float* __restrict__ msg)
{
    const int i = blockIdx.x;
    const int t = threadIdx.x;
    int s = row_start[i], e = row_start[i + 1];
    if (s >= e) return;
    const uint_t* pp = (const uint_t*)p;
    int k = s, kend = e;
    float lo[8] = {}, hi[8] = {};
    for (; k + 8 <= kend; k += 8) {
        uint_t v[8];
        #pragma unroll
        for (int q = 0; q < 8; ++q) v[q] = pp[(size_t)(k + q) * 64 + t];
        #pragma unroll
        for (int q = 0; q < 8; ++q) {
            lo[q] += __uint_as_float(v[q] << 16);
            hi[q] += __uint_as_float(v[q] & 0xFFFF0000u);
        }
    }
    for (; k < kend; ++k) {
        uint_t v = pp[(size_t)k * 64 + t];
        lo[0] += __uint_as_float(v << 16); hi[0] += __uint_as_float(v & 0xFFFF0000u);
    }
    float a0 = ((lo[0]+lo[1])+(lo[2]+lo[3])) + ((lo[4]+lo[5])+(lo[6]+lo[7]));
    float a1 = ((hi[0]+hi[1])+(hi[2]+hi[3])) + ((hi[4]+hi[5])+(hi[6]+hi[7]));
    float2* mp = (float2*)&msg[(size_t)i * FDIM + 2 * t];
    float2 mv = *mp;
    mv.x += a0; mv.y += a1;
    *mp = mv;
}

// ---------------------------------------------------------------------------
// Fallback fused edge kernel (tiny-ws only)
// ---------------------------------------------------------------------------
__global__ __launch_bounds__(128) void k_edge(
    const float* __restrict__ desc,
    const int* __restrict__ idx_i,
    const int* __restrict__ idx_j,
    const float* __restrict__ Wdesc,
    const ushort_t* __restrict__ xja,
    float* __restrict__ msg)
{
    const int i = blockIdx.x;
    const int t = threadIdx.x;
    int lo = 0, hi = NE;
    while (lo < hi) { int mid = (lo + hi) >> 1; if (idx_i[mid] < i) lo = mid + 1; else hi = mid; }
    int start = lo;
    hi = NE;
    while (lo < hi) { int mid = (lo + hi) >> 1; if (idx_i[mid] < i + 1) lo = mid + 1; else hi = mid; }
    int end = lo;
    start = __builtin_amdgcn_readfirstlane(start);
    end   = __builtin_amdgcn_readfirstlane(end);
    if (start >= end) return;
    float wreg[KDIM];
    #pragma unroll
    for (int q = 0; q < KDIM / 4; ++q) {
        float4 wv = *(const float4*)(Wdesc + (size_t)t * KDIM + 4 * q);
        wreg[4*q+0] = wv.x; wreg[4*q+1] = wv.y; wreg[4*q+2] = wv.z; wreg[4*q+3] = wv.w;
    }
    float acc = 0.0f;
    for (int e = start; e < end; ++e) {
        int jj = idx_j[e];
        const float* de = desc + (size_t)e * KDIM;
        float dot = 0.0f;
        #pragma unroll
        for (int q = 0; q < KDIM / 4; ++q) {
            float4 dv = *(const float4*)(de + 4 * q);
            dot += dv.x * wreg[4*q] + dv.y * wreg[4*q+1]
                 + dv.z * wreg[4*q+2] + dv.w * wreg[4*q+3];
        }
        acc += dot * bf2f(xja[(size_t)jj * FDIM + t]);
    }
    msg[(size_t)i * FDIM + t] += acc;
}

// ---------------------------------------------------------------------------
// Fused node chain (transposed): 3 residuals + outmix + 2 residuals.
// m carried as f32x4[8] per thread (atom fixed per lane, features packed).
// ---------------------------------------------------------------------------
__global__ __launch_bounds__(256) void k_chain(
    const float* __restrict__ msgp, const float* __restrict__ feat,
    const float* __restrict__ u, const ushort_t* __restrict__ wch,
    const float* __restrict__ bri1, const float* __restrict__ bri2,
    const float* __restrict__ bd,
    const float* __restrict__ bra1, const float* __restrict__ bra2,
    float* __restrict__ xout)
{
    __shared__ ushort_t actA[64][136];
    __shared__ ushort_t wlds[128][136];
    const int t = threadIdx.x, lane = t & 63, w = t >> 6;
    const int lrow = lane & 15, kgrp = lane >> 4;
    const int atom = blockIdx.x * 64 + 16 * w + lrow;
    const bool ok = atom < NA;

    f32x4 m[8], h[8], acc[8];
    #pragma unroll
    for (int nf = 0; nf < 8; ++nf)
        m[nf] = ok ? *(const f32x4*)(msgp + (size_t)atom * FDIM + 16 * nf + 4 * kgrp)
                   : (f32x4){0.f, 0.f, 0.f, 0.f};

    // --- 3 interaction residuals ---
    for (int k = 0; k < NRI; ++k) {
        write_act_T(actA, w, lrow, kgrp, m);
        __syncthreads();
        stage_w(wch + (size_t)(2 * k) * 16384, wlds, t);
        __syncthreads();
        gemm_tile_T(actA, wlds, w, lrow, kgrp, bri1 + k * FDIM, acc);
        #pragma unroll
        for (int nf = 0; nf < 8; ++nf) h[nf] = acc[nf];
        write_act_T(actA, w, lrow, kgrp, h);
        __syncthreads();
        stage_w(wch + (size_t)(2 * k + 1) * 16384, wlds, t);
        __syncthreads();
        gemm_tile_T(actA, wlds, w, lrow, kgrp, bri2 + k * FDIM, acc);
        #pragma unroll
        for (int nf = 0; nf < 8; ++nf) m[nf] += acc[nf];
    }

    // --- outmix: m = u*feat + ssp(m)@Wd.T + bd ---
    write_act_T(actA, w, lrow, kgrp, m);
    __syncthreads();
    stage_w(wch + (size_t)6 * 16384, wlds, t);
    __syncthreads();
    gemm_tile_T(actA, wlds, w, lrow, kgrp, bd, acc);
    #pragma unroll
    for (int nf = 0; nf < 8; ++nf) {
        f32x4 fv = ok ? *(const f32x4*)(feat + (size_t)atom * FDIM + 16 * nf + 4 * kgrp)
                      : (f32x4){0.f, 0.f, 0.f, 0.f};
        f32x4 uv = *(const f32x4*)(u + 16 * nf + 4 * kgrp);
        m[nf] = uv * fv + acc[nf];
    }

    // --- 2 atomic residuals ---
    for (int k = 0; k < NRA; ++k) {
        write_act_T(actA, w, lrow, kgrp, m);
        __syncthreads();
        stage_w(wch + (size_t)(7 + 2 * k) * 16384, wlds, t);
        __syncthreads();
        gemm_tile_T(actA, wlds, w, lrow, kgrp, bra1 + k * FDIM, acc);
        #pragma unroll
        for (int nf = 0; nf < 8; ++nf) h[nf] = acc[nf];
        write_act_T(actA, w, lrow, kgrp, h);
        __syncthreads();
        stage_w(wch + (size_t)(8 + 2 * k) * 16384, wlds, t);
        __syncthreads();
        gemm_tile_T(actA, wlds, w, lrow, kgrp, bra2 + k * FDIM, acc);
        #pragma unroll
        for (int nf = 0; nf < 8; ++nf) m[nf] += acc[nf];
    }

    if (ok)
        #pragma unroll
        for (int nf = 0; nf < 8; ++nf)
            *(f32x4*)(xout + (size_t)atom * FDIM + 16 * nf + 4 * kgrp) = m[nf];
}

// ---------------------------------------------------------------------------
extern "C" void kernel_launch(void* const* d_in, const int* in_sizes, int n_in,
                              void* d_out, int out_size, void* d_ws, size_t ws_size,
                              hipStream_t stream)
{
    const float* feat  = (const float*)d_in[0];
    const float* desc  = (const float*)d_in[1];
    const int*   idx_i = (const int*)d_in[2];
    const int*   idx_j = (const int*)d_in[3];
    const float* Wdesc = (const float*)d_in[4];
    const float* Wi    = (const float*)d_in[5];
    const float* bi    = (const float*)d_in[6];
    const float* Wj    = (const float*)d_in[7];
    const float* bj    = (const float*)d_in[8];
    const float* Wri1  = (const float*)d_in[9];
    const float* bri1  = (const float*)d_in[10];
    const float* Wri2  = (const float*)d_in[11];
    const float* bri2  = (const float*)d_in[12];
    const float* Wd    = (const float*)d_in[13];
    const float* bd    = (const float*)d_in[14];
    const float* u     = (const float*)d_in[15];
    const float* Wra1  = (const float*)d_in[16];
    const float* bra1  = (const float*)d_in[17];
    const float* Wra2  = (const float*)d_in[18];
    const float* bra2  = (const float*)d_in[19];

    char* wsp = (char*)d_ws;
    float* msg = (float*)wsp;
    size_t off = (size_t)NA * FDIM * sizeof(float);
    ushort_t* xja = (ushort_t*)(wsp + off);
    off += (size_t)NA * FDIM * sizeof(ushort_t);
    int* row_start = (int*)(wsp + off);
    off += (((size_t)(NA + 1) * sizeof(int)) + 255) & ~(size_t)255;
    ushort_t* wbf = (ushort_t*)(wsp + off);
    off += (((size_t)221184 * sizeof(ushort_t)) + 255) & ~(size_t)255;
    ushort_t* gbuf = (ushort_t*)(wsp + off);
    size_t avail = (ws_size > off) ? ws_size - off : 0;
    int full_fit = (avail >= (size_t)NE * FDIM * sizeof(ushort_t));

    float* xout = (float*)d_out;
    const int nblk64 = (NA + 63) / 64;

    k_wconv<<<dim3(24, 8), 256, 0, stream>>>(Wdesc, Wi, Wj, Wri1, Wri2, Wd, Wra1, Wra2, wbf);
    k_row_starts<<<(NA + 256) / 256, 256, 0, stream>>>(idx_i, row_start);
    k_node_pre<<<nblk64, 256, 0, stream>>>(feat, wbf, bi, bj, msg, xja);

    if (full_fit) {
        const int EPB = 4 * TPW * 16;   // 512 edges per block
        k_gemm_p<<<(NE + EPB - 1) / EPB, 256, 0, stream>>>(desc, wbf, idx_j, xja, gbuf, NE);
        k_segsum<<<NA, 64, 0, stream>>>(gbuf, row_start, msg);
    } else {
        k_edge<<<NA, 128, 0, stream>>>(desc, idx_i, idx_j, Wdesc, xja, msg);
    }

    k_chain<<<nblk64, 256, 0, stream>>>(msg, feat, u, wbf + 40960,
                                        bri1, bri2, bd, bra1, bra2, xout);
}

// Round 9
// 286.461 us; speedup vs baseline: 1.3506x; 1.1995x over previous
//
#include <hip/hip_runtime.h>
#include <math.h>

#define NA 50000
#define NE 800000
#define FDIM 128
#define KDIM 64
#define NRI 3
#define NRA 2

typedef unsigned short ushort_t;
typedef unsigned int uint_t;
typedef __attribute__((ext_vector_type(8))) short short8v;
typedef __attribute__((ext_vector_type(4))) float f32x4;
typedef __attribute__((ext_vector_type(4))) unsigned short u16x4;

// ssp(x) = softplus(x) - ln2 via hardware v_exp_f32/v_log_f32.
__device__ __forceinline__ float ssp_f(float x) {
    float e = __expf(-fabsf(x));
    return fmaxf(x, 0.0f) + __logf(1.0f + e) - 0.69314718055994530942f;
}
__device__ __forceinline__ ushort_t f2bf(float x) {
    unsigned u = __float_as_uint(x);
    u += 0x7FFFu + ((u >> 16) & 1u);          // RNE
    return (ushort_t)(u >> 16);
}
__device__ __forceinline__ float bf2f(ushort_t h) {
    return __uint_as_float(((unsigned)h) << 16);
}
__device__ __forceinline__ f32x4 ssp4(f32x4 v) {
    f32x4 r;
    #pragma unroll
    for (int j = 0; j < 4; ++j) r[j] = ssp_f(v[j]);
    return r;
}
__device__ __forceinline__ u16x4 pack4(f32x4 v) {
    u16x4 p;
    #pragma unroll
    for (int j = 0; j < 4; ++j) p[j] = f2bf(v[j]);
    return p;
}

// ---------------------------------------------------------------------------
// Weight pre-convert (once): fp32 -> bf16 into ws.
// wbf layout (ushort offsets): Wdesc@0 (8192), Wi@8192, Wj@24576,
// chain@40960: [Wri1_0,Wri2_0,Wri1_1,Wri2_1,Wri1_2,Wri2_2,Wd,Wra1_0,Wra2_0,Wra1_1,Wra2_1]
// ---------------------------------------------------------------------------
__global__ __launch_bounds__(256) void k_wconv(
    const float* __restrict__ Wdesc, const float* __restrict__ Wi,
    const float* __restrict__ Wj,    const float* __restrict__ Wri1,
    const float* __restrict__ Wri2,  const float* __restrict__ Wd,
    const float* __restrict__ Wra1,  const float* __restrict__ Wra2,
    ushort_t* __restrict__ wbf)
{
    const int seg = blockIdx.y;
    const int idx = blockIdx.x * 2048 + threadIdx.x * 8;
    const float* s; ushort_t* d; int cnt;
    const int CH = 40960;
    switch (seg) {
    case 0: cnt = 8192;  if (idx >= cnt) return; s = Wdesc + idx; d = wbf + idx; break;
    case 1: cnt = 16384; if (idx >= cnt) return; s = Wi + idx;    d = wbf + 8192 + idx; break;
    case 2: cnt = 16384; if (idx >= cnt) return; s = Wj + idx;    d = wbf + 24576 + idx; break;
    case 3: { cnt = 3*16384; if (idx >= cnt) return; int k = idx/16384, o = idx - k*16384;
              s = Wri1 + idx; d = wbf + CH + (2*k)*16384 + o; break; }
    case 4: { cnt = 3*16384; if (idx >= cnt) return; int k = idx/16384, o = idx - k*16384;
              s = Wri2 + idx; d = wbf + CH + (2*k+1)*16384 + o; break; }
    case 5: cnt = 16384; if (idx >= cnt) return; s = Wd + idx; d = wbf + CH + 6*16384 + idx; break;
    case 6: { cnt = 2*16384; if (idx >= cnt) return; int k = idx/16384, o = idx - k*16384;
              s = Wra1 + idx; d = wbf + CH + (7+2*k)*16384 + o; break; }
    default:{ cnt = 2*16384; if (idx >= cnt) return; int k = idx/16384, o = idx - k*16384;
              s = Wra2 + idx; d = wbf + CH + (8+2*k)*16384 + o; break; }
    }
    #pragma unroll
    for (int j = 0; j < 8; ++j) d[j] = f2bf(s[j]);
}

// ---------------------------------------------------------------------------
// Transposed-GEMM helpers. Wave w owns atoms {16w + lrow}; each lane holds
// features {16nf + 4kgrp + r} of its atom. C[row=W-row(feature)][col=act-row(atom)].
// ---------------------------------------------------------------------------
__device__ __forceinline__ void stage_w(const ushort_t* __restrict__ src,
                                        ushort_t (*wlds)[136], int t)
{
    const int r = t >> 1, c0 = (t & 1) * 64;
    const short8v* s = (const short8v*)(src + (size_t)r * FDIM + c0);
    #pragma unroll
    for (int q = 0; q < 8; ++q)
        *(short8v*)&wlds[r][c0 + q * 8] = s[q];
}

__device__ __forceinline__ void gemm_tile_T(
    const ushort_t (*actA)[136], const ushort_t (*wlds)[136],
    int w, int lrow, int kgrp, const float* __restrict__ bias, f32x4 acc[8])
{
    short8v bfr[4];
    #pragma unroll
    for (int ks = 0; ks < 4; ++ks)
        bfr[ks] = *(const short8v*)&actA[16 * w + lrow][ks * 32 + kgrp * 8];
    #pragma unroll
    for (int nf = 0; nf < 8; ++nf)
        acc[nf] = *(const f32x4*)(bias + 16 * nf + 4 * kgrp);
    #pragma unroll
    for (int nf = 0; nf < 8; ++nf)
        #pragma unroll
        for (int ks = 0; ks < 4; ++ks) {
            short8v av = *(const short8v*)&wlds[16 * nf + lrow][ks * 32 + kgrp * 8];
            acc[nf] = __builtin_amdgcn_mfma_f32_16x16x32_bf16(av, bfr[ks], acc[nf], 0, 0, 0);
        }
}

// act = ssp(v), packed b64 writes into this wave's own 16 rows
__device__ __forceinline__ void write_act_T(
    ushort_t (*actA)[136], int w, int lrow, int kgrp, const f32x4 v[8])
{
    #pragma unroll
    for (int nf = 0; nf < 8; ++nf)
        *(u16x4*)&actA[16 * w + lrow][16 * nf + 4 * kgrp] = pack4(ssp4(v[nf]));
}

// ---------------------------------------------------------------------------
// Node pre (MFMA, transposed): xi = ssp(ssp(feat)@Wi.T+bi) -> msg (f32)
//                              xja = ssp(ssp(feat)@Wj.T+bj) -> bf16
// ---------------------------------------------------------------------------
__global__ __launch_bounds__(256) void k_node_pre(
    const float* __restrict__ feat, const ushort_t* __restrict__ wbf,
    const float* __restrict__ bi, const float* __restrict__ bj,
    float* __restrict__ xi_out, ushort_t* __restrict__ xja_out)
{
    __shared__ ushort_t actA[64][136];
    __shared__ ushort_t wlds[128][136];
    const int t = threadIdx.x, lane = t & 63, w = t >> 6;
    const int lrow = lane & 15, kgrp = lane >> 4;
    const int atom = blockIdx.x * 64 + 16 * w + lrow;
    const bool ok = atom < NA;

    f32x4 v[8];
    #pragma unroll
    for (int nf = 0; nf < 8; ++nf)
        v[nf] = ok ? *(const f32x4*)(feat + (size_t)atom * FDIM + 16 * nf + 4 * kgrp)
                   : (f32x4){0.f, 0.f, 0.f, 0.f};
    write_act_T(actA, w, lrow, kgrp, v);
    __syncthreads();
    stage_w(wbf + 8192, wlds, t);
    __syncthreads();
    f32x4 acc[8];
    gemm_tile_T(actA, wlds, w, lrow, kgrp, bi, acc);
    if (ok)
        #pragma unroll
        for (int nf = 0; nf < 8; ++nf)
            *(f32x4*)(xi_out + (size_t)atom * FDIM + 16 * nf + 4 * kgrp) = ssp4(acc[nf]);
    __syncthreads();
    stage_w(wbf + 24576, wlds, t);
    __syncthreads();
    gemm_tile_T(actA, wlds, w, lrow, kgrp, bj, acc);
    if (ok)
        #pragma unroll
        for (int nf = 0; nf < 8; ++nf)
            *(u16x4*)(xja_out + (size_t)atom * FDIM + 16 * nf + 4 * kgrp) = pack4(ssp4(acc[nf]));
}

// ---------------------------------------------------------------------------
// Fused edge kernel: per block of 64 contiguous edges,
//   p[e][f] = (desc[e]@Wdesc[f]) * xja[idx_j[e]][f]   (MFMA, f32 in LDS)
// then feature-parallel segmented sum over the 64 rows (idx_i sorted ->
// contiguous runs), flushed with native f32 atomics into msg.
// Eliminates the 410 MB p round-trip through HBM.
// ---------------------------------------------------------------------------
__device__ __forceinline__ short8v pack8(const float* p) {
    short8v r;
    #pragma unroll
    for (int j = 0; j < 8; ++j) r[j] = (short)f2bf(p[j]);
    return r;
}

__global__ __launch_bounds__(256) void k_edge_fused(
    const float* __restrict__ desc, const ushort_t* __restrict__ wdbf,
    const int* __restrict__ idx_i, const int* __restrict__ idx_j,
    const ushort_t* __restrict__ xja,
    float* __restrict__ msg)
{
    __shared__ float pl[64][136];   // f32 p tile; stride 136 -> ~4-way write aliasing
    __shared__ int ii[64];
    const int t = threadIdx.x, lane = t & 63, w = t >> 6;
    const int lrow = lane & 15, kgrp = lane >> 4;
    const int e0 = blockIdx.x * 64;
    const int er = e0 + w * 16 + lrow;          // this lane's edge (always < NE: 64|NE)

    if (t < 64) ii[t] = idx_i[e0 + t];

    // Wdesc A-fragments (bf16, L2-hot)
    short8v a[8][2];
    #pragma unroll
    for (int nf = 0; nf < 8; ++nf)
        #pragma unroll
        for (int ks = 0; ks < 2; ++ks)
            a[nf][ks] = *(const short8v*)(wdbf + (size_t)(16 * nf + lrow) * KDIM
                                          + ks * 32 + kgrp * 8);

    const int jj = idx_j[er];

    // desc B-fragments
    const float* q = desc + (size_t)er * KDIM + kgrp * 8;
    float t0[8], t1[8];
    *(float4*)(t0)     = *(const float4*)q;
    *(float4*)(t0 + 4) = *(const float4*)(q + 4);
    *(float4*)(t1)     = *(const float4*)(q + 32);
    *(float4*)(t1 + 4) = *(const float4*)(q + 36);
    short8v b0 = pack8(t0), b1 = pack8(t1);

    f32x4 acc[8];
    #pragma unroll
    for (int nf = 0; nf < 8; ++nf) acc[nf] = (f32x4){0.f, 0.f, 0.f, 0.f};
    #pragma unroll
    for (int nf = 0; nf < 8; ++nf) {
        acc[nf] = __builtin_amdgcn_mfma_f32_16x16x32_bf16(a[nf][0], b0, acc[nf], 0,0,0);
        acc[nf] = __builtin_amdgcn_mfma_f32_16x16x32_bf16(a[nf][1], b1, acc[nf], 0,0,0);
    }

    // gather-multiply, park in LDS (f32 -- p is never rounded to bf16 now)
    #pragma unroll
    for (int nf = 0; nf < 8; ++nf) {
        u16x4 xv = *(const u16x4*)(xja + (size_t)jj * FDIM + 16 * nf + 4 * kgrp);
        f32x4 pr;
        #pragma unroll
        for (int j = 0; j < 4; ++j) pr[j] = acc[nf][j] * bf2f(xv[j]);
        *(f32x4*)&pl[w * 16 + lrow][16 * nf + 4 * kgrp] = pr;
    }
    __syncthreads();

    // segmented flush: thread = (feature, half); walk 32 rows, atomically add
    // each segment partial. idx_i sorted -> runs are contiguous.
    const int f = t & 127, h = t >> 7;
    const int r0 = h * 32, r1 = r0 + 32;
    float s = 0.0f;
    int cur = ii[r0];
    for (int r = r0; r < r1; ++r) {
        int id = ii[r];
        if (id != cur) {
            unsafeAtomicAdd(&msg[(size_t)cur * FDIM + f], s);
            s = 0.0f; cur = id;
        }
        s += pl[r][f];
    }
    unsafeAtomicAdd(&msg[(size_t)cur * FDIM + f], s);
}

// ---------------------------------------------------------------------------
// Fused node chain (transposed): 3 residuals + outmix + 2 residuals.
// m carried as f32x4[8] per thread (atom fixed per lane, features packed).
// ---------------------------------------------------------------------------
__global__ __launch_bounds__(256) void k_chain(
    const float* __restrict__ msgp, const float* __restrict__ feat,
    const float* __restrict__ u, const ushort_t* __restrict__ wch,
    const float* __restrict__ bri1, const float* __restrict__ bri2,
    const float* __restrict__ bd,
    const float* __restrict__ bra1, const float* __restrict__ bra2,
    float* __restrict__ xout)
{
    __shared__ ushort_t actA[64][136];
    __shared__ ushort_t wlds[128][136];
    const int t = threadIdx.x, lane = t & 63, w = t >> 6;
    const int lrow = lane & 15, kgrp = lane >> 4;
    const int atom = blockIdx.x * 64 + 16 * w + lrow;
    const bool ok = atom < NA;

    f32x4 m[8], h[8], acc[8];
    #pragma unroll
    for (int nf = 0; nf < 8; ++nf)
        m[nf] = ok ? *(const f32x4*)(msgp + (size_t)atom * FDIM + 16 * nf + 4 * kgrp)
                   : (f32x4){0.f, 0.f, 0.f, 0.f};

    // --- 3 interaction residuals ---
    for (int k = 0; k < NRI; ++k) {
        write_act_T(actA, w, lrow, kgrp, m);
        __syncthreads();
        stage_w(wch + (size_t)(2 * k) * 16384, wlds, t);
        __syncthreads();
        gemm_tile_T(actA, wlds, w, lrow, kgrp, bri1 + k * FDIM, acc);
        #pragma unroll
        for (int nf = 0; nf < 8; ++nf) h[nf] = acc[nf];
        write_act_T(actA, w, lrow, kgrp, h);
        __syncthreads();
        stage_w(wch + (size_t)(2 * k + 1) * 16384, wlds, t);
        __syncthreads();
        gemm_tile_T(actA, wlds, w, lrow, kgrp, bri2 + k * FDIM, acc);
        #pragma unroll
        for (int nf = 0; nf < 8; ++nf) m[nf] += acc[nf];
    }

    // --- outmix: m = u*feat + ssp(m)@Wd.T + bd ---
    write_act_T(actA, w, lrow, kgrp, m);
    __syncthreads();
    stage_w(wch + (size_t)6 * 16384, wlds, t);
    __syncthreads();
    gemm_tile_T(actA, wlds, w, lrow, kgrp, bd, acc);
    #pragma unroll
    for (int nf = 0; nf < 8; ++nf) {
        f32x4 fv = ok ? *(const f32x4*)(feat + (size_t)atom * FDIM + 16 * nf + 4 * kgrp)
                      : (f32x4){0.f, 0.f, 0.f, 0.f};
        f32x4 uv = *(const f32x4*)(u + 16 * nf + 4 * kgrp);
        m[nf] = uv * fv + acc[nf];
    }

    // --- 2 atomic residuals ---
    for (int k = 0; k < NRA; ++k) {
        write_act_T(actA, w, lrow, kgrp, m);
        __syncthreads();
        stage_w(wch + (size_t)(7 + 2 * k) * 16384, wlds, t);
        __syncthreads();
        gemm_tile_T(actA, wlds, w, lrow, kgrp, bra1 + k * FDIM, acc);
        #pragma unroll
        for (int nf = 0; nf < 8; ++nf) h[nf] = acc[nf];
        write_act_T(actA, w, lrow, kgrp, h);
        __syncthreads();
        stage_w(wch + (size_t)(8 + 2 * k) * 16384, wlds, t);
        __syncthreads();
        gemm_tile_T(actA, wlds, w, lrow, kgrp, bra2 + k * FDIM, acc);
        #pragma unroll
        for (int nf = 0; nf < 8; ++nf) m[nf] += acc[nf];
    }

    if (ok)
        #pragma unroll
        for (int nf = 0; nf < 8; ++nf)
            *(f32x4*)(xout + (size_t)atom * FDIM + 16 * nf + 4 * kgrp) = m[nf];
}

// ---------------------------------------------------------------------------
extern "C" void kernel_launch(void* const* d_in, const int* in_sizes, int n_in,
                              void* d_out, int out_size, void* d_ws, size_t ws_size,
                              hipStream_t stream)
{
    const float* feat  = (const float*)d_in[0];
    const float* desc  = (const float*)d_in[1];
    const int*   idx_i = (const int*)d_in[2];
    const int*   idx_j = (const int*)d_in[3];
    const float* Wdesc = (const float*)d_in[4];
    const float* Wi    = (const float*)d_in[5];
    const float* bi    = (const float*)d_in[6];
    const float* Wj    = (const float*)d_in[7];
    const float* bj    = (const float*)d_in[8];
    const float* Wri1  = (const float*)d_in[9];
    const float* bri1  = (const float*)d_in[10];
    const float* Wri2  = (const float*)d_in[11];
    const float* bri2  = (const float*)d_in[12];
    const float* Wd    = (const float*)d_in[13];
    const float* bd    = (const float*)d_in[14];
    const float* u     = (const float*)d_in[15];
    const float* Wra1  = (const float*)d_in[16];
    const float* bra1  = (const float*)d_in[17];
    const float* Wra2  = (const float*)d_in[18];
    const float* bra2  = (const float*)d_in[19];

    char* wsp = (char*)d_ws;
    float* msg = (float*)wsp;                             // NA*F f32
    size_t off = (size_t)NA * FDIM * sizeof(float);
    ushort_t* xja = (ushort_t*)(wsp + off);               // NA*F bf16
    off += (size_t)NA * FDIM * sizeof(ushort_t);
    ushort_t* wbf = (ushort_t*)(wsp + off);               // bf16 weights
    off += (((size_t)221184 * sizeof(ushort_t)) + 255) & ~(size_t)255;

    float* xout = (float*)d_out;
    const int nblk64 = (NA + 63) / 64;

    k_wconv<<<dim3(24, 8), 256, 0, stream>>>(Wdesc, Wi, Wj, Wri1, Wri2, Wd, Wra1, Wra2, wbf);
    k_node_pre<<<nblk64, 256, 0, stream>>>(feat, wbf, bi, bj, msg, xja);
    k_edge_fused<<<NE / 64, 256, 0, stream>>>(desc, wbf, idx_i, idx_j, xja, msg);
    k_chain<<<nblk64, 256, 0, stream>>>(msg, feat, u, wbf + 40960,
                                        bri1, bri2, bd, bra1, bra2, xout);
}